// Round 13
// baseline (2441.746 us; speedup 1.0000x reference)
//
#include <hip/hip_runtime.h>

// FeatureTokenizer — R13 FINAL DIAGNOSTIC: R11 main (unchanged, 192.7us) +
// two pure-store probes at the EXACT rocclr-fill geometry (grid 224 x 256,
// grid-stride long loop — fill shows occupancy 10.9% ~= 224 blocks):
//   Probe A: plain stores   (the fill's own config)
//   Probe B: sc1 nt stores
// This is the last untested structural cell for the fill's 6.5 TB/s.
// A >= 6.2 -> adopt small-grid geometry for main next round.
// A ~= 5.2 -> 6.5 is not HIP-reachable; R11 is the roofline.

typedef float fx4 __attribute__((ext_vector_type(4)));

constexpr int kC = 128;
constexpr int kH4 = 32;                        // fx4 per (b,c) row
constexpr int kTotal4 = 1 << 26;               // 67,108,864 fx4 outputs
constexpr int kBlock = 256;
constexpr int kGrid = 2048;
constexpr int kStride4 = kGrid * kBlock;       // 524288 fx4
constexpr int kIters = kTotal4 / kStride4;     // 128 (exact)
constexpr int kRcStep = kStride4 / kH4;        // 16384 rows (== 0 mod kC)

__global__ __launch_bounds__(kBlock) void FeatureTokenizer_69664369541889_kernel(
    const float* __restrict__ x,      // (B, C)
    const float* __restrict__ m,      // (B, C)
    const float* __restrict__ W,      // (C, H)
    const float* __restrict__ bias,   // (C, H)
    const float* __restrict__ me,     // (1, H)
    float* __restrict__ out)          // (B, C, H)
{
    const fx4* __restrict__ W4  = reinterpret_cast<const fx4*>(W);
    const fx4* __restrict__ b4  = reinterpret_cast<const fx4*>(bias);
    const fx4* __restrict__ me4 = reinterpret_cast<const fx4*>(me);
    fx4* __restrict__ out4      = reinterpret_cast<fx4*>(out);

    const int idx0 = blockIdx.x * kBlock + threadIdx.x;   // [0, 524288)
    const int h4   = idx0 & (kH4 - 1);
    int rc         = idx0 >> 5;                           // [0, 16384)
    const int cc   = rc & (kC - 1);                       // fixed per thread

    const fx4 w  = W4[cc * kH4 + h4];
    const fx4 bb = b4[cc * kH4 + h4];
    const fx4 e  = me4[h4];

    int oidx = idx0;
#pragma unroll 8
    for (int it = 0; it < kIters; ++it) {
        const float xv = x[rc];
        const float mv = m[rc];
        const float om = 1.0f - mv;

        fx4 o;
        o.x = fmaf(fmaf(xv, w.x, bb.x), om, e.x * mv);
        o.y = fmaf(fmaf(xv, w.y, bb.y), om, e.y * mv);
        o.z = fmaf(fmaf(xv, w.z, bb.z), om, e.z * mv);
        o.w = fmaf(fmaf(xv, w.w, bb.w), om, e.w * mv);

        fx4* p = &out4[oidx];
        asm volatile("global_store_dwordx4 %0, %1, off sc1 nt"
                     :: "v"(p), "v"(o));

        rc   += kRcStep;
        oidx += kStride4;
    }
}

// --- probes: exact fill geometry (grid 224, grid-stride, long loop) ---
constexpr int kGridF = 224;
constexpr long long kStrideF = (long long)kGridF * kBlock;   // 57344 fx4

__global__ __launch_bounds__(kBlock) void ws_fillmimic_plain_probe(
    fx4* __restrict__ ws, long long n4)
{
    fx4 v;
    v.x = 1.0f; v.y = 2.0f; v.z = 3.0f; v.w = 4.0f;
    const long long t0 = (long long)blockIdx.x * kBlock + threadIdx.x;
    for (int pass = 0; pass < 2; ++pass) {
        for (long long idx = t0; idx < n4; idx += kStrideF) {
            ws[idx] = v;                       // plain store, rocclr-style
        }
    }
}

__global__ __launch_bounds__(kBlock) void ws_fillmimic_nt_probe(
    fx4* __restrict__ ws, long long n4)
{
    fx4 v;
    v.x = 1.0f; v.y = 2.0f; v.z = 3.0f; v.w = 4.0f;
    const long long t0 = (long long)blockIdx.x * kBlock + threadIdx.x;
    for (int pass = 0; pass < 2; ++pass) {
        for (long long idx = t0; idx < n4; idx += kStrideF) {
            fx4* p = &ws[idx];
            asm volatile("global_store_dwordx4 %0, %1, off sc1 nt"
                         :: "v"(p), "v"(v));
        }
    }
}

extern "C" void kernel_launch(void* const* d_in, const int* in_sizes, int n_in,
                              void* d_out, int out_size, void* d_ws, size_t ws_size,
                              hipStream_t stream) {
    const float* x    = (const float*)d_in[0];  // x_numerical (B, C)
    const float* m    = (const float*)d_in[1];  // mask (B, C)
    const float* W    = (const float*)d_in[2];  // W (C, H)
    const float* bias = (const float*)d_in[3];  // b (C, H)
    const float* me   = (const float*)d_in[4];  // mask_embedding (1, H)
    float* out        = (float*)d_out;

    FeatureTokenizer_69664369541889_kernel<<<kGrid, kBlock, 0, stream>>>(
        x, m, W, bias, me, out);

    long long n4 = (long long)(ws_size / 16);
    const long long cap = 3LL * (long long)kTotal4;   // 3.22 GB of fx4
    if (n4 > cap) n4 = cap;
    if (n4 > 0) {
        ws_fillmimic_plain_probe<<<kGridF, kBlock, 0, stream>>>((fx4*)d_ws, n4);
        ws_fillmimic_nt_probe<<<kGridF, kBlock, 0, stream>>>((fx4*)d_ws, n4);
    }
}

// Round 14
// 330.964 us; speedup vs baseline: 7.3777x; 7.3777x over previous
//
#include <hip/hip_runtime.h>

// FeatureTokenizer — R14: R11 + small grid (the last open cell).
//
// Probe matrix (pure store, TB/s): plain/2048=5.19, plain/224=5.97,
// nt/2048=4.93, nt/224=5.51 -> small grid raises store rate ~12-15%.
// R11 (nt, grid 2048) = 192.7us (5.66 TB/s effective). This round: same
// kernel, grid 256 (1 block/CU, 4 waves/CU). If the probes' small-grid
// advantage transfers with loads present, ~172us; if TLP loss dominates
// (R6's plain-store pattern), it regresses and R11 is the roofline.

typedef float fx4 __attribute__((ext_vector_type(4)));

constexpr int kC = 128;
constexpr int kH4 = 32;                        // fx4 per (b,c) row
constexpr int kTotal4 = 1 << 26;               // 67,108,864 fx4 outputs
constexpr int kBlock = 256;
constexpr int kGrid = 256;                     // 1 block/CU
constexpr int kStride4 = kGrid * kBlock;       // 65536 fx4
constexpr int kIters = kTotal4 / kStride4;     // 1024 (exact)
constexpr int kRcStep = kStride4 / kH4;        // 2048 rows (== 0 mod kC)

__global__ __launch_bounds__(kBlock) void FeatureTokenizer_69664369541889_kernel(
    const float* __restrict__ x,      // (B, C)
    const float* __restrict__ m,      // (B, C)
    const float* __restrict__ W,      // (C, H)
    const float* __restrict__ bias,   // (C, H)
    const float* __restrict__ me,     // (1, H)
    float* __restrict__ out)          // (B, C, H)
{
    const fx4* __restrict__ W4  = reinterpret_cast<const fx4*>(W);
    const fx4* __restrict__ b4  = reinterpret_cast<const fx4*>(bias);
    const fx4* __restrict__ me4 = reinterpret_cast<const fx4*>(me);
    fx4* __restrict__ out4      = reinterpret_cast<fx4*>(out);

    const int idx0 = blockIdx.x * kBlock + threadIdx.x;   // [0, 65536)
    const int h4   = idx0 & (kH4 - 1);
    int rc         = idx0 >> 5;                           // [0, 2048)
    const int cc   = rc & (kC - 1);                       // fixed per thread

    // Loop-invariant per-thread tables (L2-resident).
    const fx4 w  = W4[cc * kH4 + h4];
    const fx4 bb = b4[cc * kH4 + h4];
    const fx4 e  = me4[h4];

    int oidx = idx0;
#pragma unroll 8
    for (int it = 0; it < kIters; ++it) {
        const float xv = x[rc];       // 32 lanes broadcast same dword
        const float mv = m[rc];
        const float om = 1.0f - mv;

        fx4 o;
        o.x = fmaf(fmaf(xv, w.x, bb.x), om, e.x * mv);
        o.y = fmaf(fmaf(xv, w.y, bb.y), om, e.y * mv);
        o.z = fmaf(fmaf(xv, w.z, bb.z), om, e.z * mv);
        o.w = fmaf(fmaf(xv, w.w, bb.w), om, e.w * mv);

        fx4* p = &out4[oidx];
        asm volatile("global_store_dwordx4 %0, %1, off sc1 nt"
                     :: "v"(p), "v"(o));

        rc   += kRcStep;
        oidx += kStride4;
    }
}

extern "C" void kernel_launch(void* const* d_in, const int* in_sizes, int n_in,
                              void* d_out, int out_size, void* d_ws, size_t ws_size,
                              hipStream_t stream) {
    const float* x    = (const float*)d_in[0];  // x_numerical (B, C)
    const float* m    = (const float*)d_in[1];  // mask (B, C)
    const float* W    = (const float*)d_in[2];  // W (C, H)
    const float* bias = (const float*)d_in[3];  // b (C, H)
    const float* me   = (const float*)d_in[4];  // mask_embedding (1, H)
    float* out        = (float*)d_out;

    FeatureTokenizer_69664369541889_kernel<<<kGrid, kBlock, 0, stream>>>(
        x, m, W, bias, me, out);
}

// Round 15
// 192.659 us; speedup vs baseline: 12.6739x; 1.7179x over previous
//
#include <hip/hip_runtime.h>

// FeatureTokenizer — R15: restore R11 (the winner) byte-identical.
//
// out[b,c,h] = (x[b,c]*W[c,h] + b[c,h])*(1-m[b,c]) + me[h]*m[b,c]
// B=16384, C=128, H=128 -> 1.074 GB f32 output, write-BW-bound.
//
// Final structure: grid 2048 x 256 (32 waves/CU for load-latency hiding),
// (c,h4) loop-invariant per thread (W/b/me hoisted, L2-resident), inner
// loop = {2 broadcast dword loads, 8 FMA, 1 streaming 16B store}, x8 unroll.
// The store uses `sc1 nt` (device-scope non-temporal): it does NOT raise
// the raw store rate (probes: nt is ~5% SLOWER pure-store) but removes
// dirty-line L2 interference against the x/m read stream -> +21% vs plain
// (233.4 -> 192.7us, 5.66 TB/s effective vs 6.5 rocclr-fill / 5.97 best
// HIP pure-store ceiling).
//
// Tested & closed: geometry (grid-stride/dense/chunked/1-store-thread),
// concurrency (4..32 waves/CU: small grid regresses with loads present),
// load elimination (shfl), SW pipelining, plain-nt builtin. R11 is the
// practical HIP roofline for this op on MI355X.

typedef float fx4 __attribute__((ext_vector_type(4)));

constexpr int kC = 128;
constexpr int kH4 = 32;                        // fx4 per (b,c) row
constexpr int kTotal4 = 1 << 26;               // 67,108,864 fx4 outputs
constexpr int kBlock = 256;
constexpr int kGrid = 2048;
constexpr int kStride4 = kGrid * kBlock;       // 524288 fx4
constexpr int kIters = kTotal4 / kStride4;     // 128 (exact)
constexpr int kRcStep = kStride4 / kH4;        // 16384 rows (== 0 mod kC)

__global__ __launch_bounds__(kBlock) void FeatureTokenizer_69664369541889_kernel(
    const float* __restrict__ x,      // (B, C)
    const float* __restrict__ m,      // (B, C)
    const float* __restrict__ W,      // (C, H)
    const float* __restrict__ bias,   // (C, H)
    const float* __restrict__ me,     // (1, H)
    float* __restrict__ out)          // (B, C, H)
{
    const fx4* __restrict__ W4  = reinterpret_cast<const fx4*>(W);
    const fx4* __restrict__ b4  = reinterpret_cast<const fx4*>(bias);
    const fx4* __restrict__ me4 = reinterpret_cast<const fx4*>(me);
    fx4* __restrict__ out4      = reinterpret_cast<fx4*>(out);

    const int idx0 = blockIdx.x * kBlock + threadIdx.x;   // [0, 524288)
    const int h4   = idx0 & (kH4 - 1);
    int rc         = idx0 >> 5;                           // [0, 16384)
    const int cc   = rc & (kC - 1);                       // fixed per thread

    // Loop-invariant per-thread tables (L2-resident).
    const fx4 w  = W4[cc * kH4 + h4];
    const fx4 bb = b4[cc * kH4 + h4];
    const fx4 e  = me4[h4];

    int oidx = idx0;
#pragma unroll 8
    for (int it = 0; it < kIters; ++it) {
        const float xv = x[rc];       // 32 lanes broadcast same dword
        const float mv = m[rc];
        const float om = 1.0f - mv;

        fx4 o;
        o.x = fmaf(fmaf(xv, w.x, bb.x), om, e.x * mv);
        o.y = fmaf(fmaf(xv, w.y, bb.y), om, e.y * mv);
        o.z = fmaf(fmaf(xv, w.z, bb.z), om, e.z * mv);
        o.w = fmaf(fmaf(xv, w.w, bb.w), om, e.w * mv);

        fx4* p = &out4[oidx];
        asm volatile("global_store_dwordx4 %0, %1, off sc1 nt"
                     :: "v"(p), "v"(o));

        rc   += kRcStep;
        oidx += kStride4;
    }
}

extern "C" void kernel_launch(void* const* d_in, const int* in_sizes, int n_in,
                              void* d_out, int out_size, void* d_ws, size_t ws_size,
                              hipStream_t stream) {
    const float* x    = (const float*)d_in[0];  // x_numerical (B, C)
    const float* m    = (const float*)d_in[1];  // mask (B, C)
    const float* W    = (const float*)d_in[2];  // W (C, H)
    const float* bias = (const float*)d_in[3];  // b (C, H)
    const float* me   = (const float*)d_in[4];  // mask_embedding (1, H)
    float* out        = (float*)d_out;

    FeatureTokenizer_69664369541889_kernel<<<kGrid, kBlock, 0, stream>>>(
        x, m, W, bias, me, out);
}